// Round 5
// baseline (21785.492 us; speedup 1.0000x reference)
//
#include <hip/hip_runtime.h>
#include <hip/hip_bf16.h>
#include <math.h>

typedef __attribute__((ext_vector_type(8))) short short8;
typedef __attribute__((ext_vector_type(4))) float f32x4;
typedef __attribute__((ext_vector_type(2))) float f32x2;

#define Bb 64
#define Tt 512
#define Ee 512
#define Hh 1024
#define G3 3072
#define KK 2048
#define NL 4
#define NSTEP (Tt + NL - 1)   // 515

#define ENC_OUT_ELEMS ((size_t)Bb * Tt * Hh)                  // 33554432
#define ENC_ST_OFF    ENC_OUT_ELEMS
#define PAD_OFF       (ENC_OUT_ELEMS + (size_t)NL * Bb * Hh)  // 33816576

static __device__ __forceinline__ float bf2f(short v) {
    union { unsigned u; float f; } c; c.u = ((unsigned)(unsigned short)v) << 16; return c.f;
}
static __device__ __forceinline__ short f2bf(float f) {
    union { float f; unsigned u; } c; c.f = f;
    unsigned u = c.u;
    unsigned r = (u + 0x7FFFu + ((u >> 16) & 1u)) >> 16;  // RNE
    return (short)r;
}
static __device__ __forceinline__ float ldbias(const void* p, size_t i, bool f32m) {
    return f32m ? ((const float*)p)[i] : bf2f(((const short*)p)[i]);
}
static __device__ __forceinline__ int ldx(const void* x, size_t i, bool x64m) {
    return x64m ? (int)((const long long*)x)[i] : ((const int*)x)[i];
}

// ---------------------------------------------------------------------------
// Dtype probes (unchanged).
// ---------------------------------------------------------------------------
__global__ void detect_mode(unsigned* __restrict__ flag,
                            const unsigned* __restrict__ w,
                            const unsigned* __restrict__ xw)
{
    if (blockIdx.x == 0 && threadIdx.x == 0) {
        int cf = 0, cx = 0;
        for (int i = 0; i < 64; ++i) {
            unsigned e = (w[i] >> 7) & 0xFFu;
            if (e >= 100u && e <= 126u) ++cf;
            if (xw[2 * i + 1] == 0u) ++cx;
        }
        flag[0] = (cf >= 32) ? 0u : 1u;
        flag[1] = (cx >= 32) ? 1u : 0u;
    }
}

// ---------------------------------------------------------------------------
// Weight transpose+concat into bf16 (unchanged).
// ---------------------------------------------------------------------------
__global__ void transpose_weights(short* __restrict__ BT,
                                  const void* __restrict__ Wh0,
                                  const void* __restrict__ WhA,
                                  const void* __restrict__ Wx0,
                                  const void* __restrict__ WxA,
                                  const unsigned* __restrict__ flag)
{
    const bool f32m = (flag[0] != 0u);
    unsigned idx = blockIdx.x * 256u + threadIdx.x;   // 4*3072*256 = 3,145,728
    unsigned n  = idx % 3072u;
    unsigned r  = idx / 3072u;
    unsigned k8 = r & 255u;
    unsigned l  = r >> 8;
    unsigned k  = k8 * 8u;

    short8 v;
    #pragma unroll
    for (int j = 0; j < 8; ++j) v[j] = 0;

    const void* base = 0;
    size_t eoff = 0;
    if (k < 1024u) {
        base = (l == 0) ? Wh0 : WhA;
        eoff = ((l == 0) ? 0 : (size_t)(l - 1) * Hh * G3) + (size_t)k * G3 + n;
    } else {
        unsigned kx = k - 1024u;
        unsigned Kx = (l == 0) ? 512u : 1024u;
        if (kx < Kx) {
            base = (l == 0) ? Wx0 : WxA;
            eoff = ((l == 0) ? 0 : (size_t)(l - 1) * Hh * G3) + (size_t)kx * G3 + n;
        }
    }
    if (base) {
        if (f32m) {
            const float* src = (const float*)base + eoff;
            #pragma unroll
            for (int j = 0; j < 8; ++j) v[j] = f2bf(src[(size_t)j * G3]);
        } else {
            const short* src = (const short*)base + eoff;
            #pragma unroll
            for (int j = 0; j < 8; ++j) v[j] = src[(size_t)j * G3];
        }
    }
    *(short8*)(BT + ((size_t)l * G3 + n) * KK + k) = v;
}

// Seed Astate[buf0][layer0] x-part with emb[x[:,0]] (unchanged)
__global__ void embed0_kernel(short* __restrict__ Astate,
                              const void* __restrict__ emb,
                              const void* __restrict__ x,
                              const unsigned* __restrict__ flag)
{
    const bool f32m = (flag[0] != 0u);
    const bool x64m = (flag[1] != 0u);
    const int b = blockIdx.x;
    const int xv = ldx(x, (size_t)b * Tt, x64m);     // t = 0
    unsigned* dst = (unsigned*)(Astate + (size_t)b * KK + Hh);
    if (f32m) {
        const f32x2* src = (const f32x2*)((const float*)emb + (size_t)xv * Ee);
        f32x2 v = src[threadIdx.x];
        dst[threadIdx.x] = ((unsigned)(unsigned short)f2bf(v.y) << 16)
                         | (unsigned)(unsigned short)f2bf(v.x);
    } else {
        const unsigned* src = (const unsigned*)((const short*)emb + (size_t)xv * Ee);
        dst[threadIdx.x] = src[threadIdx.x];
    }
}

__global__ void padmask_kernel(float* __restrict__ out,
                               const void* __restrict__ x,
                               const unsigned* __restrict__ flag)
{
    const bool x64m = (flag[1] != 0u);
    const int i = blockIdx.x * 256 + threadIdx.x;   // 32768 total
    out[PAD_OFF + i] = (ldx(x, i, x64m) != 0) ? 1.0f : 0.0f;
}

// ---------------------------------------------------------------------------
// Persistent wavefront GRU scan.
//   * Weights/biases/h register-resident (R3). Bank-conflict-free red[] (R4).
//   * Barrier: RELAXED polls + single trailing acquire fence (R4).
//   * NEW (R5): ALL cross-step-visible stores are NON-TEMPORAL (enc_out,
//     enc_states, awrow, awnext, emb prefetch). They bypass the local L2 and
//     complete at the memory side, so the release-RMW's buffer_wbl2 finds a
//     clean L2 (the ~38 us/step wbl2 dirty-writeback disappears) and each
//     wave's pre-__syncthreads vmcnt(0) alone guarantees global visibility.
// ---------------------------------------------------------------------------
__global__ void __launch_bounds__(256, 1) gru_scan(
    const short* __restrict__ BT, short* __restrict__ Astate,
    unsigned* __restrict__ bar,
    const void* __restrict__ x, const void* __restrict__ emb,
    const void* __restrict__ bx0, const void* __restrict__ bh0,
    const void* __restrict__ bxA, const void* __restrict__ bhA,
    float* __restrict__ out, const unsigned* __restrict__ flag)
{
    const bool f32m = (flag[0] != 0u);
    const bool x64m = (flag[1] != 0u);
    const int tid  = threadIdx.x;
    const int bi   = blockIdx.x;
    const int l    = bi >> 6;
    const int cb   = bi & 63;
    const int c0   = cb * 16;
    const int wv   = tid >> 6;
    const int lane = tid & 63;
    const int l15  = lane & 15;
    const int q    = lane >> 4;

    // [wave][frag][G=li>>4][j=li&15 (+1 pad)][reg] — G-stride 68 floats
    __shared__ float red[4][12][4][17][4];   // 52224 B

    const void* bxp; const void* bhp; size_t boff;
    if (l == 0) { bxp = bx0; bhp = bh0; boff = 0; }
    else        { bxp = bxA; bhp = bhA; boff = (size_t)(l - 1) * G3; }
    const short* BTl = BT + (size_t)l * G3 * KK;

    const int kbase = wv * 512 + q * 8;

    // ---- weights resident in registers: 48 frags x 16B = 192 VGPRs ----
    short8 breg[48];
    {
        const short* brow0 = BTl + (size_t)(c0 + l15) * KK + kbase;
        #pragma unroll
        for (int ks = 0; ks < 16; ++ks) {
            const int ko = ks * 32;
            breg[ks * 3 + 0] = *(const short8*)(brow0 + ko);
            breg[ks * 3 + 1] = *(const short8*)(brow0 + (size_t)Hh * KK + ko);
            breg[ks * 3 + 2] = *(const short8*)(brow0 + (size_t)(2 * Hh) * KK + ko);
        }
    }

    // epilogue mapping: thread -> (row = tid&63, 4 cols j = (tid>>6)*4 + jj)
    const int erow    = tid & 63;
    const int ejq     = tid >> 6;
    const int m_tile  = erow >> 4;
    const int Gi      = (erow & 12) >> 2;   // li>>4 of old layout
    const int reg     = erow & 3;

    // ---- biases hoisted to registers (loop-invariant) ----
    float bsr[4], bsz[4], bgn[4], bxn[4];
    #pragma unroll
    for (int jj = 0; jj < 4; ++jj) {
        const int c = c0 + ejq * 4 + jj;
        bsr[jj] = ldbias(bxp, boff + c, f32m)           + ldbias(bhp, boff + c, f32m);
        bsz[jj] = ldbias(bxp, boff + Hh + c, f32m)      + ldbias(bhp, boff + Hh + c, f32m);
        bgn[jj] = ldbias(bhp, boff + 2 * Hh + c, f32m);
        bxn[jj] = ldbias(bxp, boff + 2 * Hh + c, f32m);
    }

    // ---- running h for this thread's 4 output elements (block-private) ----
    float hreg[4] = {0.f, 0.f, 0.f, 0.f};

    for (int s = 0; s < NSTEP; ++s) {
        const int t = s - l;
        const bool active = (t >= 0) && (t < Tt);
        const int rbuf = s & 1;
        short*       Aw = Astate + ((size_t)(rbuf ^ 1) * NL + l) * Bb * KK;
        const short* Ar = Astate + ((size_t)rbuf       * NL + l) * Bb * KK;

        f32x4 acc[4][3];
        if (active) {
            // layer-0 blocks prefetch next timestep's embedding row (batch cb)
            if (l == 0 && t + 1 < Tt) {
                const int xv = ldx(x, (size_t)cb * Tt + t + 1, x64m);
                unsigned* dstu = (unsigned*)(Aw + (size_t)cb * KK + Hh);
                if (f32m) {
                    const f32x2* srcf = (const f32x2*)((const float*)emb + (size_t)xv * Ee);
                    f32x2 v = srcf[tid];
                    unsigned pk = ((unsigned)(unsigned short)f2bf(v.y) << 16)
                                | (unsigned)(unsigned short)f2bf(v.x);
                    __builtin_nontemporal_store(pk, &dstu[tid]);
                } else {
                    const unsigned* srcu = (const unsigned*)((const short*)emb + (size_t)xv * Ee);
                    __builtin_nontemporal_store(srcu[tid], &dstu[tid]);
                }
            }
            #pragma unroll
            for (int m = 0; m < 4; ++m)
                #pragma unroll
                for (int g = 0; g < 3; ++g)
                    acc[m][g] = (f32x4){0.f, 0.f, 0.f, 0.f};

            const short* arow0 = Ar + (size_t)l15 * KK + kbase;

            #pragma unroll
            for (int ks = 0; ks < 16; ++ks) {
                const int ko = ks * 32;
                short8 af0 = *(const short8*)(arow0 + ko);
                short8 af1 = *(const short8*)(arow0 + 16 * KK + ko);
                short8 af2 = *(const short8*)(arow0 + 32 * KK + ko);
                short8 af3 = *(const short8*)(arow0 + 48 * KK + ko);
                #pragma unroll
                for (int g = 0; g < 3; ++g) {
                    acc[0][g] = __builtin_amdgcn_mfma_f32_16x16x32_bf16(
                        af0, breg[ks * 3 + g], acc[0][g], 0, 0, 0);
                    acc[1][g] = __builtin_amdgcn_mfma_f32_16x16x32_bf16(
                        af1, breg[ks * 3 + g], acc[1][g], 0, 0, 0);
                    acc[2][g] = __builtin_amdgcn_mfma_f32_16x16x32_bf16(
                        af2, breg[ks * 3 + g], acc[2][g], 0, 0, 0);
                    acc[3][g] = __builtin_amdgcn_mfma_f32_16x16x32_bf16(
                        af3, breg[ks * 3 + g], acc[3][g], 0, 0, 0);
                }
            }
            #pragma unroll
            for (int m = 0; m < 4; ++m)
                #pragma unroll
                for (int g = 0; g < 3; ++g)
                    *(f32x4*)(&red[wv][m * 3 + g][lane >> 4][lane & 15][0]) = acc[m][g];
        }
        __syncthreads();

        if (active) {
            short* awrow = Aw + (size_t)erow * KK;
            short* awnext = (l < 3)
                ? (Astate + ((size_t)(rbuf ^ 1) * NL + (l + 1)) * Bb * KK
                   + (size_t)erow * KK + Hh)
                : (short*)0;
            #pragma unroll
            for (int jj = 0; jj < 4; ++jj) {
                const int j  = ejq * 4 + jj;
                const int fr = m_tile * 3;
                float sr = red[0][fr][Gi][j][reg] + red[1][fr][Gi][j][reg]
                         + red[2][fr][Gi][j][reg] + red[3][fr][Gi][j][reg];
                float sz = red[0][fr+1][Gi][j][reg] + red[1][fr+1][Gi][j][reg]
                         + red[2][fr+1][Gi][j][reg] + red[3][fr+1][Gi][j][reg];
                float gn = red[0][fr+2][Gi][j][reg] + red[1][fr+2][Gi][j][reg];
                float xn = red[2][fr+2][Gi][j][reg] + red[3][fr+2][Gi][j][reg];
                const int c = c0 + j;
                sr += bsr[jj];
                sz += bsz[jj];
                gn += bgn[jj];
                xn += bxn[jj];
                const float r  = 1.f / (1.f + __expf(-sr));
                const float z  = 1.f / (1.f + __expf(-sz));
                const float nn = tanhf(xn + r * gn);
                const float hp = hreg[jj];
                const float hn = (1.f - z) * nn + z * hp;
                hreg[jj] = hn;
                const short hb = f2bf(hn);
                __builtin_nontemporal_store(hb, &awrow[c]);          // own recurrence
                if (l < 3) __builtin_nontemporal_store(hb, &awnext[c]); // next layer in
                else __builtin_nontemporal_store(hn,
                        &out[((size_t)erow * Tt + t) * Hh + c]);     // enc_out (f32)
                if (t == Tt - 1)
                    __builtin_nontemporal_store(hn,
                        &out[ENC_ST_OFF + ((size_t)l * Bb + erow) * Hh + c]);
            }
        }

        // ---- grid barrier: release add; RELAXED polls; one acquire fence.
        // Escalation to acquire-polls after 512 spins guarantees progress
        // even if relaxed agent-scope loads were served stale.
        __syncthreads();
        if (tid == 0) {
            __hip_atomic_fetch_add(bar, 1u, __ATOMIC_RELEASE, __HIP_MEMORY_SCOPE_AGENT);
            const unsigned target = 256u * (unsigned)(s + 1);
            unsigned spins = 0;
            while (__hip_atomic_load(bar, __ATOMIC_RELAXED, __HIP_MEMORY_SCOPE_AGENT) < target) {
                __builtin_amdgcn_s_sleep(16);
                if (++spins > 512u) {   // insurance: known-good acquire polls
                    while (__hip_atomic_load(bar, __ATOMIC_ACQUIRE, __HIP_MEMORY_SCOPE_AGENT) < target) {
                        __builtin_amdgcn_s_sleep(16);
                    }
                    break;
                }
            }
            __builtin_amdgcn_fence(__ATOMIC_ACQUIRE, "agent");
        }
        __syncthreads();
    }
}

extern "C" void kernel_launch(void* const* d_in, const int* in_sizes, int n_in,
                              void* d_out, int out_size, void* d_ws, size_t ws_size,
                              hipStream_t stream)
{
    const void* x   = d_in[0];
    const void* emb = d_in[1];
    const void* Wx0 = d_in[2];
    const void* Wh0 = d_in[3];
    const void* bx0 = d_in[4];
    const void* bh0 = d_in[5];
    const void* WxA = d_in[6];
    const void* WhA = d_in[7];
    const void* bxA = d_in[8];
    const void* bhA = d_in[9];
    float* out = (float*)d_out;

    char* ws = (char*)d_ws;
    const size_t ASTATE_BYTES = (size_t)2 * NL * Bb * KK * 2;   // 2 MiB
    unsigned* bar  = (unsigned*)ws;                      // ws+0
    unsigned* flag = (unsigned*)(ws + 64);               // ws+64 (2 words)
    short* Astate  = (short*)(ws + 256);
    short* BT      = (short*)(ws + 256 + ASTATE_BYTES);  // 48 MiB

    // zero barrier + flags + state (h(-1)=0, layer-0 x-pad stays 0 forever)
    hipMemsetAsync(ws, 0, 256 + ASTATE_BYTES, stream);

    hipLaunchKernelGGL(detect_mode, dim3(1), dim3(64), 0, stream,
                       flag, (const unsigned*)Wx0, (const unsigned*)x);
    hipLaunchKernelGGL(transpose_weights, dim3(12288), dim3(256), 0, stream,
                       (short*)BT, Wh0, WhA, Wx0, WxA, flag);
    hipLaunchKernelGGL(embed0_kernel, dim3(64), dim3(256), 0, stream,
                       Astate, emb, x, flag);
    hipLaunchKernelGGL(padmask_kernel, dim3(128), dim3(256), 0, stream,
                       out, x, flag);

    // ---- robust launch of the persistent scan (proven in R3) --------------
    void* args[] = { (void*)&BT, (void*)&Astate, (void*)&bar,
                     (void*)&x, (void*)&emb, (void*)&bx0, (void*)&bh0,
                     (void*)&bxA, (void*)&bhA, (void*)&out, (void*)&flag };

    int maxBlocksPerCU = 0;
    hipError_t oe = hipOccupancyMaxActiveBlocksPerMultiprocessor(
        &maxBlocksPerCU, gru_scan, 256, 0);

    hipError_t ce = hipErrorUnknown;
    if (oe == hipSuccess && maxBlocksPerCU >= 1) {
        ce = hipLaunchCooperativeKernel((void*)gru_scan, dim3(256), dim3(256),
                                        args, 0, stream);
    }
    if (ce != hipSuccess) {
        hipLaunchKernelGGL(gru_scan, dim3(256), dim3(256), 0, stream,
                           (const short*)BT, Astate, bar, x, emb,
                           bx0, bh0, bxA, bhA, out, (const unsigned*)flag);
    }
}

// Round 6
// 12880.898 us; speedup vs baseline: 1.6913x; 1.6913x over previous
//
#include <hip/hip_runtime.h>
#include <hip/hip_bf16.h>
#include <math.h>

typedef __attribute__((ext_vector_type(8))) short short8;
typedef __attribute__((ext_vector_type(4))) float f32x4;
typedef __attribute__((ext_vector_type(2))) float f32x2;

#define Bb 64
#define Tt 512
#define Ee 512
#define Hh 1024
#define G3 3072
#define KK 2048
#define NL 4
#define NSTEP (Tt + NL - 1)   // 515
#define NBLK 256

#define ENC_OUT_ELEMS ((size_t)Bb * Tt * Hh)                  // 33554432
#define ENC_ST_OFF    ENC_OUT_ELEMS
#define PAD_OFF       (ENC_OUT_ELEMS + (size_t)NL * Bb * Hh)  // 33816576

static __device__ __forceinline__ float bf2f(short v) {
    union { unsigned u; float f; } c; c.u = ((unsigned)(unsigned short)v) << 16; return c.f;
}
static __device__ __forceinline__ short f2bf(float f) {
    union { float f; unsigned u; } c; c.f = f;
    unsigned u = c.u;
    unsigned r = (u + 0x7FFFu + ((u >> 16) & 1u)) >> 16;  // RNE
    return (short)r;
}
static __device__ __forceinline__ float ldbias(const void* p, size_t i, bool f32m) {
    return f32m ? ((const float*)p)[i] : bf2f(((const short*)p)[i]);
}
static __device__ __forceinline__ int ldx(const void* x, size_t i, bool x64m) {
    return x64m ? (int)((const long long*)x)[i] : ((const int*)x)[i];
}

// ---------------------------------------------------------------------------
// Dtype probes (unchanged).
// ---------------------------------------------------------------------------
__global__ void detect_mode(unsigned* __restrict__ flag,
                            const unsigned* __restrict__ w,
                            const unsigned* __restrict__ xw)
{
    if (blockIdx.x == 0 && threadIdx.x == 0) {
        int cf = 0, cx = 0;
        for (int i = 0; i < 64; ++i) {
            unsigned e = (w[i] >> 7) & 0xFFu;
            if (e >= 100u && e <= 126u) ++cf;
            if (xw[2 * i + 1] == 0u) ++cx;
        }
        flag[0] = (cf >= 32) ? 0u : 1u;
        flag[1] = (cx >= 32) ? 1u : 0u;
    }
}

// ---------------------------------------------------------------------------
// Weight transpose+concat into bf16 (unchanged).
// ---------------------------------------------------------------------------
__global__ void transpose_weights(short* __restrict__ BT,
                                  const void* __restrict__ Wh0,
                                  const void* __restrict__ WhA,
                                  const void* __restrict__ Wx0,
                                  const void* __restrict__ WxA,
                                  const unsigned* __restrict__ flag)
{
    const bool f32m = (flag[0] != 0u);
    unsigned idx = blockIdx.x * 256u + threadIdx.x;   // 4*3072*256 = 3,145,728
    unsigned n  = idx % 3072u;
    unsigned r  = idx / 3072u;
    unsigned k8 = r & 255u;
    unsigned l  = r >> 8;
    unsigned k  = k8 * 8u;

    short8 v;
    #pragma unroll
    for (int j = 0; j < 8; ++j) v[j] = 0;

    const void* base = 0;
    size_t eoff = 0;
    if (k < 1024u) {
        base = (l == 0) ? Wh0 : WhA;
        eoff = ((l == 0) ? 0 : (size_t)(l - 1) * Hh * G3) + (size_t)k * G3 + n;
    } else {
        unsigned kx = k - 1024u;
        unsigned Kx = (l == 0) ? 512u : 1024u;
        if (kx < Kx) {
            base = (l == 0) ? Wx0 : WxA;
            eoff = ((l == 0) ? 0 : (size_t)(l - 1) * Hh * G3) + (size_t)kx * G3 + n;
        }
    }
    if (base) {
        if (f32m) {
            const float* src = (const float*)base + eoff;
            #pragma unroll
            for (int j = 0; j < 8; ++j) v[j] = f2bf(src[(size_t)j * G3]);
        } else {
            const short* src = (const short*)base + eoff;
            #pragma unroll
            for (int j = 0; j < 8; ++j) v[j] = src[(size_t)j * G3];
        }
    }
    *(short8*)(BT + ((size_t)l * G3 + n) * KK + k) = v;
}

// Seed Astate[buf0][layer0] x-part with emb[x[:,0]] (unchanged)
__global__ void embed0_kernel(short* __restrict__ Astate,
                              const void* __restrict__ emb,
                              const void* __restrict__ x,
                              const unsigned* __restrict__ flag)
{
    const bool f32m = (flag[0] != 0u);
    const bool x64m = (flag[1] != 0u);
    const int b = blockIdx.x;
    const int xv = ldx(x, (size_t)b * Tt, x64m);     // t = 0
    unsigned* dst = (unsigned*)(Astate + (size_t)b * KK + Hh);
    if (f32m) {
        const f32x2* src = (const f32x2*)((const float*)emb + (size_t)xv * Ee);
        f32x2 v = src[threadIdx.x];
        dst[threadIdx.x] = ((unsigned)(unsigned short)f2bf(v.y) << 16)
                         | (unsigned)(unsigned short)f2bf(v.x);
    } else {
        const unsigned* src = (const unsigned*)((const short*)emb + (size_t)xv * Ee);
        dst[threadIdx.x] = src[threadIdx.x];
    }
}

__global__ void padmask_kernel(float* __restrict__ out,
                               const void* __restrict__ x,
                               const unsigned* __restrict__ flag)
{
    const bool x64m = (flag[1] != 0u);
    const int i = blockIdx.x * 256 + threadIdx.x;   // 32768 total
    out[PAD_OFF + i] = (ldx(x, i, x64m) != 0) ? 1.0f : 0.0f;
}

// ---------------------------------------------------------------------------
// Persistent wavefront GRU scan.
//   * Weights/biases/h register-resident (R3). Conflict-free red[] (R4).
//   * Data-path stores: plain (R4 form; R5's NT experiment reverted).
//   * NEW (R6): distributed store-based grid barrier — NO atomic RMW on a
//     shared line. Arrival = relaxed store to a per-block 128B slot (256
//     parallel lines); block 0 gathers with 256 threads (one slot each),
//     then publishes a single release word; all blocks poll it read-only.
//     The R4 barrier's 256 serialized fetch_adds on one line (~150ns each
//     ≈ 38us/step, the whole residual) disappear.
// ---------------------------------------------------------------------------
__global__ void __launch_bounds__(256, 1) gru_scan(
    const short* __restrict__ BT, short* __restrict__ Astate,
    unsigned* __restrict__ rel, unsigned* __restrict__ arrive,
    const void* __restrict__ x, const void* __restrict__ emb,
    const void* __restrict__ bx0, const void* __restrict__ bh0,
    const void* __restrict__ bxA, const void* __restrict__ bhA,
    float* __restrict__ out, const unsigned* __restrict__ flag)
{
    const bool f32m = (flag[0] != 0u);
    const bool x64m = (flag[1] != 0u);
    const int tid  = threadIdx.x;
    const int bi   = blockIdx.x;
    const int l    = bi >> 6;
    const int cb   = bi & 63;
    const int c0   = cb * 16;
    const int wv   = tid >> 6;
    const int lane = tid & 63;
    const int l15  = lane & 15;
    const int q    = lane >> 4;

    // [wave][frag][G=li>>4][j=li&15 (+1 pad)][reg] — G-stride 68 floats
    __shared__ float red[4][12][4][17][4];   // 52224 B

    const void* bxp; const void* bhp; size_t boff;
    if (l == 0) { bxp = bx0; bhp = bh0; boff = 0; }
    else        { bxp = bxA; bhp = bhA; boff = (size_t)(l - 1) * G3; }
    const short* BTl = BT + (size_t)l * G3 * KK;

    const int kbase = wv * 512 + q * 8;

    // ---- weights resident in registers: 48 frags x 16B = 192 VGPRs ----
    short8 breg[48];
    {
        const short* brow0 = BTl + (size_t)(c0 + l15) * KK + kbase;
        #pragma unroll
        for (int ks = 0; ks < 16; ++ks) {
            const int ko = ks * 32;
            breg[ks * 3 + 0] = *(const short8*)(brow0 + ko);
            breg[ks * 3 + 1] = *(const short8*)(brow0 + (size_t)Hh * KK + ko);
            breg[ks * 3 + 2] = *(const short8*)(brow0 + (size_t)(2 * Hh) * KK + ko);
        }
    }

    // epilogue mapping: thread -> (row = tid&63, 4 cols j = (tid>>6)*4 + jj)
    const int erow    = tid & 63;
    const int ejq     = tid >> 6;
    const int m_tile  = erow >> 4;
    const int Gi      = (erow & 12) >> 2;   // li>>4 of old layout
    const int reg     = erow & 3;

    // ---- biases hoisted to registers (loop-invariant) ----
    float bsr[4], bsz[4], bgn[4], bxn[4];
    #pragma unroll
    for (int jj = 0; jj < 4; ++jj) {
        const int c = c0 + ejq * 4 + jj;
        bsr[jj] = ldbias(bxp, boff + c, f32m)           + ldbias(bhp, boff + c, f32m);
        bsz[jj] = ldbias(bxp, boff + Hh + c, f32m)      + ldbias(bhp, boff + Hh + c, f32m);
        bgn[jj] = ldbias(bhp, boff + 2 * Hh + c, f32m);
        bxn[jj] = ldbias(bxp, boff + 2 * Hh + c, f32m);
    }

    // ---- running h for this thread's 4 output elements (block-private) ----
    float hreg[4] = {0.f, 0.f, 0.f, 0.f};

    for (int s = 0; s < NSTEP; ++s) {
        const int t = s - l;
        const bool active = (t >= 0) && (t < Tt);
        const int rbuf = s & 1;
        short*       Aw = Astate + ((size_t)(rbuf ^ 1) * NL + l) * Bb * KK;
        const short* Ar = Astate + ((size_t)rbuf       * NL + l) * Bb * KK;

        f32x4 acc[4][3];
        if (active) {
            // layer-0 blocks prefetch next timestep's embedding row (batch cb)
            if (l == 0 && t + 1 < Tt) {
                const int xv = ldx(x, (size_t)cb * Tt + t + 1, x64m);
                unsigned* dstu = (unsigned*)(Aw + (size_t)cb * KK + Hh);
                if (f32m) {
                    const f32x2* srcf = (const f32x2*)((const float*)emb + (size_t)xv * Ee);
                    f32x2 v = srcf[tid];
                    dstu[tid] = ((unsigned)(unsigned short)f2bf(v.y) << 16)
                              | (unsigned)(unsigned short)f2bf(v.x);
                } else {
                    const unsigned* srcu = (const unsigned*)((const short*)emb + (size_t)xv * Ee);
                    dstu[tid] = srcu[tid];
                }
            }
            #pragma unroll
            for (int m = 0; m < 4; ++m)
                #pragma unroll
                for (int g = 0; g < 3; ++g)
                    acc[m][g] = (f32x4){0.f, 0.f, 0.f, 0.f};

            const short* arow0 = Ar + (size_t)l15 * KK + kbase;

            #pragma unroll
            for (int ks = 0; ks < 16; ++ks) {
                const int ko = ks * 32;
                short8 af0 = *(const short8*)(arow0 + ko);
                short8 af1 = *(const short8*)(arow0 + 16 * KK + ko);
                short8 af2 = *(const short8*)(arow0 + 32 * KK + ko);
                short8 af3 = *(const short8*)(arow0 + 48 * KK + ko);
                #pragma unroll
                for (int g = 0; g < 3; ++g) {
                    acc[0][g] = __builtin_amdgcn_mfma_f32_16x16x32_bf16(
                        af0, breg[ks * 3 + g], acc[0][g], 0, 0, 0);
                    acc[1][g] = __builtin_amdgcn_mfma_f32_16x16x32_bf16(
                        af1, breg[ks * 3 + g], acc[1][g], 0, 0, 0);
                    acc[2][g] = __builtin_amdgcn_mfma_f32_16x16x32_bf16(
                        af2, breg[ks * 3 + g], acc[2][g], 0, 0, 0);
                    acc[3][g] = __builtin_amdgcn_mfma_f32_16x16x32_bf16(
                        af3, breg[ks * 3 + g], acc[3][g], 0, 0, 0);
                }
            }
            #pragma unroll
            for (int m = 0; m < 4; ++m)
                #pragma unroll
                for (int g = 0; g < 3; ++g)
                    *(f32x4*)(&red[wv][m * 3 + g][lane >> 4][lane & 15][0]) = acc[m][g];
        }
        __syncthreads();

        if (active) {
            short* awrow = Aw + (size_t)erow * KK;
            short* awnext = (l < 3)
                ? (Astate + ((size_t)(rbuf ^ 1) * NL + (l + 1)) * Bb * KK
                   + (size_t)erow * KK + Hh)
                : (short*)0;
            #pragma unroll
            for (int jj = 0; jj < 4; ++jj) {
                const int j  = ejq * 4 + jj;
                const int fr = m_tile * 3;
                float sr = red[0][fr][Gi][j][reg] + red[1][fr][Gi][j][reg]
                         + red[2][fr][Gi][j][reg] + red[3][fr][Gi][j][reg];
                float sz = red[0][fr+1][Gi][j][reg] + red[1][fr+1][Gi][j][reg]
                         + red[2][fr+1][Gi][j][reg] + red[3][fr+1][Gi][j][reg];
                float gn = red[0][fr+2][Gi][j][reg] + red[1][fr+2][Gi][j][reg];
                float xn = red[2][fr+2][Gi][j][reg] + red[3][fr+2][Gi][j][reg];
                const int c = c0 + j;
                sr += bsr[jj];
                sz += bsz[jj];
                gn += bgn[jj];
                xn += bxn[jj];
                const float r  = 1.f / (1.f + __expf(-sr));
                const float z  = 1.f / (1.f + __expf(-sz));
                const float nn = tanhf(xn + r * gn);
                const float hp = hreg[jj];
                const float hn = (1.f - z) * nn + z * hp;
                hreg[jj] = hn;
                const short hb = f2bf(hn);
                awrow[c] = hb;                                   // own recurrence
                if (l < 3) awnext[c] = hb;                       // next layer input
                else out[((size_t)erow * Tt + t) * Hh + c] = hn; // enc_out (f32)
                if (t == Tt - 1)
                    out[ENC_ST_OFF + ((size_t)l * Bb + erow) * Hh + c] = hn;
            }
        }

        if (s == NSTEP - 1) break;   // nothing depends on the final barrier

        // ---- distributed store-based grid barrier (no RMW) ----
        __syncthreads();
        const unsigned su = (unsigned)(s + 1);
        if (tid == 0) {
            __builtin_amdgcn_fence(__ATOMIC_RELEASE, "agent");   // flush this XCD's dirty lines
            __hip_atomic_store(&arrive[(size_t)bi * 32], su,
                               __ATOMIC_RELAXED, __HIP_MEMORY_SCOPE_AGENT);
        }
        if (bi == 0) {
            // 256 threads gather 256 per-block arrival slots in parallel
            unsigned spins = 0;
            while (__hip_atomic_load(&arrive[(size_t)tid * 32],
                                     __ATOMIC_RELAXED, __HIP_MEMORY_SCOPE_AGENT) < su) {
                __builtin_amdgcn_s_sleep(1);
                if (++spins > 4096u)
                    __builtin_amdgcn_fence(__ATOMIC_ACQUIRE, "agent"); // insurance
            }
            __syncthreads();
            if (tid == 0) {
                __builtin_amdgcn_fence(__ATOMIC_ACQ_REL, "agent");
                __hip_atomic_store(rel, su, __ATOMIC_RELAXED, __HIP_MEMORY_SCOPE_AGENT);
            }
        }
        if (tid == 0) {
            unsigned spins = 0;
            while (__hip_atomic_load(rel, __ATOMIC_RELAXED, __HIP_MEMORY_SCOPE_AGENT) < su) {
                __builtin_amdgcn_s_sleep(4);
                if (++spins > 4096u)
                    __builtin_amdgcn_fence(__ATOMIC_ACQUIRE, "agent"); // insurance
            }
            __builtin_amdgcn_fence(__ATOMIC_ACQUIRE, "agent");
        }
        __syncthreads();
    }
}

extern "C" void kernel_launch(void* const* d_in, const int* in_sizes, int n_in,
                              void* d_out, int out_size, void* d_ws, size_t ws_size,
                              hipStream_t stream)
{
    const void* x   = d_in[0];
    const void* emb = d_in[1];
    const void* Wx0 = d_in[2];
    const void* Wh0 = d_in[3];
    const void* bx0 = d_in[4];
    const void* bh0 = d_in[5];
    const void* WxA = d_in[6];
    const void* WhA = d_in[7];
    const void* bxA = d_in[8];
    const void* bhA = d_in[9];
    float* out = (float*)d_out;

    char* ws = (char*)d_ws;
    const size_t ASTATE_BYTES = (size_t)2 * NL * Bb * KK * 2;   // 2 MiB
    unsigned* rel    = (unsigned*)ws;                    // ws+0   (own line)
    unsigned* flag   = (unsigned*)(ws + 256);            // ws+256 (2 words)
    unsigned* arrive = (unsigned*)(ws + 4096);           // 256 x 128B = 32 KiB
    short* Astate    = (short*)(ws + 36864);
    short* BT        = (short*)(ws + 36864 + ASTATE_BYTES); // 48 MiB

    // zero rel + flags + arrive + state (h(-1)=0, layer-0 x-pad stays 0)
    hipMemsetAsync(ws, 0, 36864 + ASTATE_BYTES, stream);

    hipLaunchKernelGGL(detect_mode, dim3(1), dim3(64), 0, stream,
                       flag, (const unsigned*)Wx0, (const unsigned*)x);
    hipLaunchKernelGGL(transpose_weights, dim3(12288), dim3(256), 0, stream,
                       (short*)BT, Wh0, WhA, Wx0, WxA, flag);
    hipLaunchKernelGGL(embed0_kernel, dim3(64), dim3(256), 0, stream,
                       Astate, emb, x, flag);
    hipLaunchKernelGGL(padmask_kernel, dim3(128), dim3(256), 0, stream,
                       out, x, flag);

    // ---- robust launch of the persistent scan (proven in R3) --------------
    void* args[] = { (void*)&BT, (void*)&Astate, (void*)&rel, (void*)&arrive,
                     (void*)&x, (void*)&emb, (void*)&bx0, (void*)&bh0,
                     (void*)&bxA, (void*)&bhA, (void*)&out, (void*)&flag };

    int maxBlocksPerCU = 0;
    hipError_t oe = hipOccupancyMaxActiveBlocksPerMultiprocessor(
        &maxBlocksPerCU, gru_scan, 256, 0);

    hipError_t ce = hipErrorUnknown;
    if (oe == hipSuccess && maxBlocksPerCU >= 1) {
        ce = hipLaunchCooperativeKernel((void*)gru_scan, dim3(256), dim3(256),
                                        args, 0, stream);
    }
    if (ce != hipSuccess) {
        hipLaunchKernelGGL(gru_scan, dim3(256), dim3(256), 0, stream,
                           (const short*)BT, Astate, rel, arrive, x, emb,
                           bx0, bh0, bxA, bhA, out, (const unsigned*)flag);
    }
}

// Round 7
// 12738.769 us; speedup vs baseline: 1.7102x; 1.0112x over previous
//
#include <hip/hip_runtime.h>
#include <hip/hip_bf16.h>
#include <math.h>

typedef __attribute__((ext_vector_type(8))) short short8;
typedef __attribute__((ext_vector_type(4))) float f32x4;
typedef __attribute__((ext_vector_type(2))) float f32x2;

#define Bb 64
#define Tt 512
#define Ee 512
#define Hh 1024
#define G3 3072
#define KK 2048
#define NL 4
#define NSTEP (Tt + NL - 1)   // 515
#define NBLK 256

#define ENC_OUT_ELEMS ((size_t)Bb * Tt * Hh)                  // 33554432
#define ENC_ST_OFF    ENC_OUT_ELEMS
#define PAD_OFF       (ENC_OUT_ELEMS + (size_t)NL * Bb * Hh)  // 33816576

static __device__ __forceinline__ float bf2f(short v) {
    union { unsigned u; float f; } c; c.u = ((unsigned)(unsigned short)v) << 16; return c.f;
}
static __device__ __forceinline__ short f2bf(float f) {
    union { float f; unsigned u; } c; c.f = f;
    unsigned u = c.u;
    unsigned r = (u + 0x7FFFu + ((u >> 16) & 1u)) >> 16;  // RNE
    return (short)r;
}
static __device__ __forceinline__ float ldbias(const void* p, size_t i, bool f32m) {
    return f32m ? ((const float*)p)[i] : bf2f(((const short*)p)[i]);
}
static __device__ __forceinline__ int ldx(const void* x, size_t i, bool x64m) {
    return x64m ? (int)((const long long*)x)[i] : ((const int*)x)[i];
}

// ---------------------------------------------------------------------------
// Dtype probes (unchanged).
// ---------------------------------------------------------------------------
__global__ void detect_mode(unsigned* __restrict__ flag,
                            const unsigned* __restrict__ w,
                            const unsigned* __restrict__ xw)
{
    if (blockIdx.x == 0 && threadIdx.x == 0) {
        int cf = 0, cx = 0;
        for (int i = 0; i < 64; ++i) {
            unsigned e = (w[i] >> 7) & 0xFFu;
            if (e >= 100u && e <= 126u) ++cf;
            if (xw[2 * i + 1] == 0u) ++cx;
        }
        flag[0] = (cf >= 32) ? 0u : 1u;
        flag[1] = (cx >= 32) ? 1u : 0u;
    }
}

// ---------------------------------------------------------------------------
// Weight transpose+concat into bf16 (unchanged).
// ---------------------------------------------------------------------------
__global__ void transpose_weights(short* __restrict__ BT,
                                  const void* __restrict__ Wh0,
                                  const void* __restrict__ WhA,
                                  const void* __restrict__ Wx0,
                                  const void* __restrict__ WxA,
                                  const unsigned* __restrict__ flag)
{
    const bool f32m = (flag[0] != 0u);
    unsigned idx = blockIdx.x * 256u + threadIdx.x;   // 4*3072*256 = 3,145,728
    unsigned n  = idx % 3072u;
    unsigned r  = idx / 3072u;
    unsigned k8 = r & 255u;
    unsigned l  = r >> 8;
    unsigned k  = k8 * 8u;

    short8 v;
    #pragma unroll
    for (int j = 0; j < 8; ++j) v[j] = 0;

    const void* base = 0;
    size_t eoff = 0;
    if (k < 1024u) {
        base = (l == 0) ? Wh0 : WhA;
        eoff = ((l == 0) ? 0 : (size_t)(l - 1) * Hh * G3) + (size_t)k * G3 + n;
    } else {
        unsigned kx = k - 1024u;
        unsigned Kx = (l == 0) ? 512u : 1024u;
        if (kx < Kx) {
            base = (l == 0) ? Wx0 : WxA;
            eoff = ((l == 0) ? 0 : (size_t)(l - 1) * Hh * G3) + (size_t)kx * G3 + n;
        }
    }
    if (base) {
        if (f32m) {
            const float* src = (const float*)base + eoff;
            #pragma unroll
            for (int j = 0; j < 8; ++j) v[j] = f2bf(src[(size_t)j * G3]);
        } else {
            const short* src = (const short*)base + eoff;
            #pragma unroll
            for (int j = 0; j < 8; ++j) v[j] = src[(size_t)j * G3];
        }
    }
    *(short8*)(BT + ((size_t)l * G3 + n) * KK + k) = v;
}

// Seed Astate[buf0][layer0] x-part with emb[x[:,0]] (unchanged)
__global__ void embed0_kernel(short* __restrict__ Astate,
                              const void* __restrict__ emb,
                              const void* __restrict__ x,
                              const unsigned* __restrict__ flag)
{
    const bool f32m = (flag[0] != 0u);
    const bool x64m = (flag[1] != 0u);
    const int b = blockIdx.x;
    const int xv = ldx(x, (size_t)b * Tt, x64m);     // t = 0
    unsigned* dst = (unsigned*)(Astate + (size_t)b * KK + Hh);
    if (f32m) {
        const f32x2* src = (const f32x2*)((const float*)emb + (size_t)xv * Ee);
        f32x2 v = src[threadIdx.x];
        dst[threadIdx.x] = ((unsigned)(unsigned short)f2bf(v.y) << 16)
                         | (unsigned)(unsigned short)f2bf(v.x);
    } else {
        const unsigned* src = (const unsigned*)((const short*)emb + (size_t)xv * Ee);
        dst[threadIdx.x] = src[threadIdx.x];
    }
}

__global__ void padmask_kernel(float* __restrict__ out,
                               const void* __restrict__ x,
                               const unsigned* __restrict__ flag)
{
    const bool x64m = (flag[1] != 0u);
    const int i = blockIdx.x * 256 + threadIdx.x;   // 32768 total
    out[PAD_OFF + i] = (ldx(x, i, x64m) != 0) ? 1.0f : 0.0f;
}

// ---------------------------------------------------------------------------
// Persistent wavefront GRU scan.
//   * Weights/biases/h register-resident (R3). Conflict-free red[] (R4).
//   * Distributed store-based barrier (R6, proven).
//   * NEW (R7): deep A-load pipelining. After the acquire fence every A-line
//     is remote (~1us L3 latency) and at 1 wave/SIMD there is no TLP, so the
//     old load4->mfma12 structure serialized ~16 round trips (~15us/step).
//     Now: burst-issue 32 loads (chunk 0), then per K-step run the MFMAs and
//     immediately issue the matching chunk-1 load quartet, then drain.
//     Latency exposure drops to ~2 round trips; refill becomes BW-bound.
// ---------------------------------------------------------------------------
__global__ void __launch_bounds__(256, 1) gru_scan(
    const short* __restrict__ BT, short* __restrict__ Astate,
    unsigned* __restrict__ rel, unsigned* __restrict__ arrive,
    const void* __restrict__ x, const void* __restrict__ emb,
    const void* __restrict__ bx0, const void* __restrict__ bh0,
    const void* __restrict__ bxA, const void* __restrict__ bhA,
    float* __restrict__ out, const unsigned* __restrict__ flag)
{
    const bool f32m = (flag[0] != 0u);
    const bool x64m = (flag[1] != 0u);
    const int tid  = threadIdx.x;
    const int bi   = blockIdx.x;
    const int l    = bi >> 6;
    const int cb   = bi & 63;
    const int c0   = cb * 16;
    const int wv   = tid >> 6;
    const int lane = tid & 63;
    const int l15  = lane & 15;
    const int q    = lane >> 4;

    // [wave][frag][G=li>>4][j=li&15 (+1 pad)][reg] — G-stride 68 floats
    __shared__ float red[4][12][4][17][4];   // 52224 B

    const void* bxp; const void* bhp; size_t boff;
    if (l == 0) { bxp = bx0; bhp = bh0; boff = 0; }
    else        { bxp = bxA; bhp = bhA; boff = (size_t)(l - 1) * G3; }
    const short* BTl = BT + (size_t)l * G3 * KK;

    const int kbase = wv * 512 + q * 8;

    // ---- weights resident in registers: 48 frags x 16B = 192 regs ----
    short8 breg[48];
    {
        const short* brow0 = BTl + (size_t)(c0 + l15) * KK + kbase;
        #pragma unroll
        for (int ks = 0; ks < 16; ++ks) {
            const int ko = ks * 32;
            breg[ks * 3 + 0] = *(const short8*)(brow0 + ko);
            breg[ks * 3 + 1] = *(const short8*)(brow0 + (size_t)Hh * KK + ko);
            breg[ks * 3 + 2] = *(const short8*)(brow0 + (size_t)(2 * Hh) * KK + ko);
        }
    }

    // epilogue mapping: thread -> (row = tid&63, 4 cols j = (tid>>6)*4 + jj)
    const int erow    = tid & 63;
    const int ejq     = tid >> 6;
    const int m_tile  = erow >> 4;
    const int Gi      = (erow & 12) >> 2;   // li>>4 of old layout
    const int reg     = erow & 3;

    // ---- biases hoisted to registers (loop-invariant) ----
    float bsr[4], bsz[4], bgn[4], bxn[4];
    #pragma unroll
    for (int jj = 0; jj < 4; ++jj) {
        const int c = c0 + ejq * 4 + jj;
        bsr[jj] = ldbias(bxp, boff + c, f32m)           + ldbias(bhp, boff + c, f32m);
        bsz[jj] = ldbias(bxp, boff + Hh + c, f32m)      + ldbias(bhp, boff + Hh + c, f32m);
        bgn[jj] = ldbias(bhp, boff + 2 * Hh + c, f32m);
        bxn[jj] = ldbias(bxp, boff + 2 * Hh + c, f32m);
    }

    // ---- running h for this thread's 4 output elements (block-private) ----
    float hreg[4] = {0.f, 0.f, 0.f, 0.f};

    for (int s = 0; s < NSTEP; ++s) {
        const int t = s - l;
        const bool active = (t >= 0) && (t < Tt);
        const int rbuf = s & 1;
        short*       Aw = Astate + ((size_t)(rbuf ^ 1) * NL + l) * Bb * KK;
        const short* Ar = Astate + ((size_t)rbuf       * NL + l) * Bb * KK;

        f32x4 acc[4][3];
        if (active) {
            const short* arow0 = Ar + (size_t)l15 * KK + kbase;

            // ---- burst-issue chunk 0: 32 independent loads (ks 0..7) ----
            short8 afb[8][4];
            #pragma unroll
            for (int ks = 0; ks < 8; ++ks) {
                const int ko = ks * 32;
                afb[ks][0] = *(const short8*)(arow0 + ko);
                afb[ks][1] = *(const short8*)(arow0 + 16 * KK + ko);
                afb[ks][2] = *(const short8*)(arow0 + 32 * KK + ko);
                afb[ks][3] = *(const short8*)(arow0 + 48 * KK + ko);
            }

            // layer-0 blocks prefetch next timestep's embedding row (batch cb)
            // (issued after the critical A-burst so it doesn't delay it)
            if (l == 0 && t + 1 < Tt) {
                const int xv = ldx(x, (size_t)cb * Tt + t + 1, x64m);
                unsigned* dstu = (unsigned*)(Aw + (size_t)cb * KK + Hh);
                if (f32m) {
                    const f32x2* srcf = (const f32x2*)((const float*)emb + (size_t)xv * Ee);
                    f32x2 v = srcf[tid];
                    dstu[tid] = ((unsigned)(unsigned short)f2bf(v.y) << 16)
                              | (unsigned)(unsigned short)f2bf(v.x);
                } else {
                    const unsigned* srcu = (const unsigned*)((const short*)emb + (size_t)xv * Ee);
                    dstu[tid] = srcu[tid];
                }
            }

            #pragma unroll
            for (int m = 0; m < 4; ++m)
                #pragma unroll
                for (int g = 0; g < 3; ++g)
                    acc[m][g] = (f32x4){0.f, 0.f, 0.f, 0.f};

            short8 afc[8][4];   // chunk 1 staging (ks 8..15)

            // ---- chunk 0 MFMAs; overlap chunk-1 load issue ----
            #pragma unroll
            for (int ks = 0; ks < 8; ++ks) {
                const int ko2 = (ks + 8) * 32;
                afc[ks][0] = *(const short8*)(arow0 + ko2);
                afc[ks][1] = *(const short8*)(arow0 + 16 * KK + ko2);
                afc[ks][2] = *(const short8*)(arow0 + 32 * KK + ko2);
                afc[ks][3] = *(const short8*)(arow0 + 48 * KK + ko2);
                #pragma unroll
                for (int g = 0; g < 3; ++g) {
                    acc[0][g] = __builtin_amdgcn_mfma_f32_16x16x32_bf16(
                        afb[ks][0], breg[ks * 3 + g], acc[0][g], 0, 0, 0);
                    acc[1][g] = __builtin_amdgcn_mfma_f32_16x16x32_bf16(
                        afb[ks][1], breg[ks * 3 + g], acc[1][g], 0, 0, 0);
                    acc[2][g] = __builtin_amdgcn_mfma_f32_16x16x32_bf16(
                        afb[ks][2], breg[ks * 3 + g], acc[2][g], 0, 0, 0);
                    acc[3][g] = __builtin_amdgcn_mfma_f32_16x16x32_bf16(
                        afb[ks][3], breg[ks * 3 + g], acc[3][g], 0, 0, 0);
                }
            }
            // ---- chunk 1 MFMAs (drain) ----
            #pragma unroll
            for (int ks = 0; ks < 8; ++ks) {
                #pragma unroll
                for (int g = 0; g < 3; ++g) {
                    acc[0][g] = __builtin_amdgcn_mfma_f32_16x16x32_bf16(
                        afc[ks][0], breg[(ks + 8) * 3 + g], acc[0][g], 0, 0, 0);
                    acc[1][g] = __builtin_amdgcn_mfma_f32_16x16x32_bf16(
                        afc[ks][1], breg[(ks + 8) * 3 + g], acc[1][g], 0, 0, 0);
                    acc[2][g] = __builtin_amdgcn_mfma_f32_16x16x32_bf16(
                        afc[ks][2], breg[(ks + 8) * 3 + g], acc[2][g], 0, 0, 0);
                    acc[3][g] = __builtin_amdgcn_mfma_f32_16x16x32_bf16(
                        afc[ks][3], breg[(ks + 8) * 3 + g], acc[3][g], 0, 0, 0);
                }
            }
            #pragma unroll
            for (int m = 0; m < 4; ++m)
                #pragma unroll
                for (int g = 0; g < 3; ++g)
                    *(f32x4*)(&red[wv][m * 3 + g][lane >> 4][lane & 15][0]) = acc[m][g];
        }
        __syncthreads();

        if (active) {
            short* awrow = Aw + (size_t)erow * KK;
            short* awnext = (l < 3)
                ? (Astate + ((size_t)(rbuf ^ 1) * NL + (l + 1)) * Bb * KK
                   + (size_t)erow * KK + Hh)
                : (short*)0;
            #pragma unroll
            for (int jj = 0; jj < 4; ++jj) {
                const int j  = ejq * 4 + jj;
                const int fr = m_tile * 3;
                float sr = red[0][fr][Gi][j][reg] + red[1][fr][Gi][j][reg]
                         + red[2][fr][Gi][j][reg] + red[3][fr][Gi][j][reg];
                float sz = red[0][fr+1][Gi][j][reg] + red[1][fr+1][Gi][j][reg]
                         + red[2][fr+1][Gi][j][reg] + red[3][fr+1][Gi][j][reg];
                float gn = red[0][fr+2][Gi][j][reg] + red[1][fr+2][Gi][j][reg];
                float xn = red[2][fr+2][Gi][j][reg] + red[3][fr+2][Gi][j][reg];
                const int c = c0 + j;
                sr += bsr[jj];
                sz += bsz[jj];
                gn += bgn[jj];
                xn += bxn[jj];
                const float r  = 1.f / (1.f + __expf(-sr));
                const float z  = 1.f / (1.f + __expf(-sz));
                const float nn = tanhf(xn + r * gn);
                const float hp = hreg[jj];
                const float hn = (1.f - z) * nn + z * hp;
                hreg[jj] = hn;
                const short hb = f2bf(hn);
                awrow[c] = hb;                                   // own recurrence
                if (l < 3) awnext[c] = hb;                       // next layer input
                else out[((size_t)erow * Tt + t) * Hh + c] = hn; // enc_out (f32)
                if (t == Tt - 1)
                    out[ENC_ST_OFF + ((size_t)l * Bb + erow) * Hh + c] = hn;
            }
        }

        if (s == NSTEP - 1) break;   // nothing depends on the final barrier

        // ---- distributed store-based grid barrier (R6, unchanged) ----
        __syncthreads();
        const unsigned su = (unsigned)(s + 1);
        if (tid == 0) {
            __builtin_amdgcn_fence(__ATOMIC_RELEASE, "agent");   // flush this XCD's dirty lines
            __hip_atomic_store(&arrive[(size_t)bi * 32], su,
                               __ATOMIC_RELAXED, __HIP_MEMORY_SCOPE_AGENT);
        }
        if (bi == 0) {
            // 256 threads gather 256 per-block arrival slots in parallel
            unsigned spins = 0;
            while (__hip_atomic_load(&arrive[(size_t)tid * 32],
                                     __ATOMIC_RELAXED, __HIP_MEMORY_SCOPE_AGENT) < su) {
                __builtin_amdgcn_s_sleep(1);
                if (++spins > 4096u)
                    __builtin_amdgcn_fence(__ATOMIC_ACQUIRE, "agent"); // insurance
            }
            __syncthreads();
            if (tid == 0) {
                __builtin_amdgcn_fence(__ATOMIC_ACQ_REL, "agent");
                __hip_atomic_store(rel, su, __ATOMIC_RELAXED, __HIP_MEMORY_SCOPE_AGENT);
            }
        }
        if (tid == 0) {
            unsigned spins = 0;
            while (__hip_atomic_load(rel, __ATOMIC_RELAXED, __HIP_MEMORY_SCOPE_AGENT) < su) {
                __builtin_amdgcn_s_sleep(4);
                if (++spins > 4096u)
                    __builtin_amdgcn_fence(__ATOMIC_ACQUIRE, "agent"); // insurance
            }
            __builtin_amdgcn_fence(__ATOMIC_ACQUIRE, "agent");
        }
        __syncthreads();
    }
}

extern "C" void kernel_launch(void* const* d_in, const int* in_sizes, int n_in,
                              void* d_out, int out_size, void* d_ws, size_t ws_size,
                              hipStream_t stream)
{
    const void* x   = d_in[0];
    const void* emb = d_in[1];
    const void* Wx0 = d_in[2];
    const void* Wh0 = d_in[3];
    const void* bx0 = d_in[4];
    const void* bh0 = d_in[5];
    const void* WxA = d_in[6];
    const void* WhA = d_in[7];
    const void* bxA = d_in[8];
    const void* bhA = d_in[9];
    float* out = (float*)d_out;

    char* ws = (char*)d_ws;
    const size_t ASTATE_BYTES = (size_t)2 * NL * Bb * KK * 2;   // 2 MiB
    unsigned* rel    = (unsigned*)ws;                    // ws+0   (own line)
    unsigned* flag   = (unsigned*)(ws + 256);            // ws+256 (2 words)
    unsigned* arrive = (unsigned*)(ws + 4096);           // 256 x 128B = 32 KiB
    short* Astate    = (short*)(ws + 36864);
    short* BT        = (short*)(ws + 36864 + ASTATE_BYTES); // 48 MiB

    // zero rel + flags + arrive + state (h(-1)=0, layer-0 x-pad stays 0)
    hipMemsetAsync(ws, 0, 36864 + ASTATE_BYTES, stream);

    hipLaunchKernelGGL(detect_mode, dim3(1), dim3(64), 0, stream,
                       flag, (const unsigned*)Wx0, (const unsigned*)x);
    hipLaunchKernelGGL(transpose_weights, dim3(12288), dim3(256), 0, stream,
                       (short*)BT, Wh0, WhA, Wx0, WxA, flag);
    hipLaunchKernelGGL(embed0_kernel, dim3(64), dim3(256), 0, stream,
                       Astate, emb, x, flag);
    hipLaunchKernelGGL(padmask_kernel, dim3(128), dim3(256), 0, stream,
                       out, x, flag);

    // ---- robust launch of the persistent scan (proven in R3) --------------
    void* args[] = { (void*)&BT, (void*)&Astate, (void*)&rel, (void*)&arrive,
                     (void*)&x, (void*)&emb, (void*)&bx0, (void*)&bh0,
                     (void*)&bxA, (void*)&bhA, (void*)&out, (void*)&flag };

    int maxBlocksPerCU = 0;
    hipError_t oe = hipOccupancyMaxActiveBlocksPerMultiprocessor(
        &maxBlocksPerCU, gru_scan, 256, 0);

    hipError_t ce = hipErrorUnknown;
    if (oe == hipSuccess && maxBlocksPerCU >= 1) {
        ce = hipLaunchCooperativeKernel((void*)gru_scan, dim3(256), dim3(256),
                                        args, 0, stream);
    }
    if (ce != hipSuccess) {
        hipLaunchKernelGGL(gru_scan, dim3(256), dim3(256), 0, stream,
                           (const short*)BT, Astate, rel, arrive, x, emb,
                           bx0, bh0, bxA, bhA, out, (const unsigned*)flag);
    }
}